// Round 5
// baseline (1390.440 us; speedup 1.0000x reference)
//
#include <hip/hip_runtime.h>
#include <cstdint>
#include <cstddef>

// Problem constants (B,S,HID,NH,IM,E fixed by the reference)
#define B_    4
#define S_    2048
#define HID_  1024
#define NH_   4
#define HD_   256     // HID/NH
#define IM_   2048
#define E_    4
#define M_    8192    // B_*S_ tokens
#define NHG_  4       // heads per attention group

typedef __bf16 bf16x8 __attribute__((ext_vector_type(8)));
typedef float  f32x4  __attribute__((ext_vector_type(4)));

__device__ __forceinline__ unsigned short f32_to_bf16(float f) {
  unsigned int u = __float_as_uint(f);
  u += 0x7fffu + ((u >> 16) & 1u);   // round-to-nearest-even
  return (unsigned short)(u >> 16);
}

// async 16B global->LDS DMA (global_load_lds_dwordx4). LDS dest is
// wave-uniform base + lane*16 -> LDS layout contiguous in lane order.
__device__ __forceinline__ void gload16(const unsigned short* g, unsigned short* l) {
  __builtin_amdgcn_global_load_lds(
      (const __attribute__((address_space(1))) void*)g,
      (__attribute__((address_space(3))) void*)l, 16, 0, 0);
}

// XCD-aware swizzle: contiguous y-bands per XCD. All call sites have
// gy % 8 == 0 or (gx*gy) covering the bijection as used in r4 (verified).
__device__ __forceinline__ void swizzle_xy(int& bx, int& by) {
  const int gx = gridDim.x, gy = gridDim.y;
  const int flat = blockIdx.x + blockIdx.y * gx;
  const int xcd = flat & 7, i = flat >> 3;
  const int rpx = gy >> 3;          // y-rows per XCD
  bx = i % gx;
  by = xcd * rpx + i / gx;
}

// ---------------- epilogue variants (generic single-B GEMM) ----------------
#define EPI_F32      0   // C fp32 (attention scores), batched via strideCz
#define EPI_VT       2   // write V^T [b][h][d][s] bf16
#define EPI_PV_O     3   // write attn O into [token][h*HD+n] bf16
#define EPI_WO       4   // out2 = add_src + acc  (h1 into d_out)
#define EPI_DOWN     5   // out2 += acc  (rw pre-folded into gu)

struct EpiAux {
  float* c_f32;
  unsigned short* c_bf16;
  const float* add_src;       // hidden (WO)
  float* out2;                // d_out (WO/DOWN)
  long long strideCz;
  int ldc;
};

// Generic batched GEMM: C[z] = A[z] (MxK, row-major, lda) @ B[z]^T.
// 128x128 tile, BK=32, 4 waves x (4x4) 16x16x32 bf16 MFMA fragments.
// Double-buffered LDS, one-iteration-ahead async global_load_lds prefetch.
template<int EPI>
__global__ __launch_bounds__(256) void gemm_bf16k(
    const unsigned short* __restrict__ A, int lda, long long sAo, long long sAi, int zbA,
    const unsigned short* __restrict__ B, int ldb, long long sBo, long long sBi, int zbB,
    int zshift, int zmask, int zbC, int K, EpiAux aux)
{
  __shared__ unsigned short As[2][128 * 32];
  __shared__ unsigned short Bs[2][128 * 32];

  const int t = threadIdx.x;
  int bx, by;
  swizzle_xy(bx, by);
  const int m0 = by * 128, n0 = bx * 128;
  const int z  = blockIdx.z;
  const int zA = z + zbA, zB = z + zbB, zC = z + zbC;
  const unsigned short* Ab = A + (long long)(zA >> zshift) * sAo + (long long)(zA & zmask) * sAi;
  const unsigned short* Bb = B + (long long)(zB >> zshift) * sBo + (long long)(zB & zmask) * sBi;

  const int lane = t & 63, wave = t >> 6;
  const int wm = (wave >> 1) * 64, wn = (wave & 1) * 64;
  const int lrow = lane & 15, quad = lane >> 4;

  f32x4 acc[4][4] = {};

  const int srow = lane >> 2;         // 0..15
  const int sko  = (lane & 3) * 8;    // k-elem 0/8/16/24
  const unsigned short* aRow0 = Ab + (long long)(m0 + wave * 16       + srow) * lda + sko;
  const unsigned short* aRow1 = Ab + (long long)(m0 + (wave + 4) * 16 + srow) * lda + sko;
  const unsigned short* bRow0 = Bb + (long long)(n0 + wave * 16       + srow) * ldb + sko;
  const unsigned short* bRow1 = Bb + (long long)(n0 + (wave + 4) * 16 + srow) * ldb + sko;
  const int dst0 = (wave * 16) * 32, dst1 = ((wave + 4) * 16) * 32;

  gload16(aRow0, &As[0][dst0]);
  gload16(aRow1, &As[0][dst1]);
  gload16(bRow0, &Bs[0][dst0]);
  gload16(bRow1, &Bs[0][dst1]);

  int cur = 0;
  for (int kk = 0; kk < K; kk += 32, cur ^= 1) {
    __syncthreads();
    if (kk + 32 < K) {
      const int nxt = cur ^ 1, k2 = kk + 32;
      gload16(aRow0 + k2, &As[nxt][dst0]);
      gload16(aRow1 + k2, &As[nxt][dst1]);
      gload16(bRow0 + k2, &Bs[nxt][dst0]);
      gload16(bRow1 + k2, &Bs[nxt][dst1]);
    }
    bf16x8 af[4], bfr[4];
    #pragma unroll
    for (int i = 0; i < 4; ++i) {
      af[i]  = *reinterpret_cast<const bf16x8*>(&As[cur][(wm + i * 16 + lrow) * 32 + quad * 8]);
      bfr[i] = *reinterpret_cast<const bf16x8*>(&Bs[cur][(wn + i * 16 + lrow) * 32 + quad * 8]);
    }
    #pragma unroll
    for (int i = 0; i < 4; ++i)
      #pragma unroll
      for (int j = 0; j < 4; ++j)
        acc[i][j] = __builtin_amdgcn_mfma_f32_16x16x32_bf16(af[i], bfr[j], acc[i][j], 0, 0, 0);
  }

  // epilogue: D row = quad*4+r, col = lane&15
  #pragma unroll
  for (int mi = 0; mi < 4; ++mi) {
    #pragma unroll
    for (int ni = 0; ni < 4; ++ni) {
      #pragma unroll
      for (int r = 0; r < 4; ++r) {
        const int gm = m0 + wm + mi * 16 + quad * 4 + r;
        const int gn = n0 + wn + ni * 16 + lrow;
        const float val = acc[mi][ni][r];
        if (EPI == EPI_F32) {
          aux.c_f32[(long long)zC * aux.strideCz + (long long)gm * aux.ldc + gn] = val;
        } else if (EPI == EPI_VT) {
          const int b = gm >> 11, s = gm & (S_ - 1);
          const int h = gn >> 8, d = gn & (HD_ - 1);
          aux.c_bf16[((long long)(b * NH_ + h) * HD_ + d) * S_ + s] = f32_to_bf16(val);
        } else if (EPI == EPI_PV_O) {
          const int b = zC >> 2, h = zC & (NH_ - 1);
          aux.c_bf16[((long long)(b * S_ + gm)) * HID_ + h * HD_ + gn] = f32_to_bf16(val);
        } else if (EPI == EPI_WO) {
          const long long idx = (long long)gm * HID_ + gn;
          aux.out2[idx] = val + aux.add_src[idx];
        } else if (EPI == EPI_DOWN) {
          const long long idx = (long long)gm * HID_ + gn;
          aux.out2[idx] += val;
        }
      }
    }
  }
}

// ---- dual-B GEMM (shared A staging, two accumulator sets, 32 MFMA/barrier)
#define EPI2_QK 0   // out0 = bf16(elu(accq)+1), out1 = bf16(elu(acck)+1), ldc=HID_
#define EPI2_GU 1   // (z? out1:out0) = bf16(silu(g)*u*rw[token][zb+z]), ldc=IM_

template<int EPI2>
__global__ __launch_bounds__(256) void gemm_dual_k(
    const unsigned short* __restrict__ A,      // [M_][HID_]
    const unsigned short* __restrict__ B0b,    // base of B0 (per-z stride sB)
    const unsigned short* __restrict__ B1b,    // base of B1
    long long sB, int zb,
    unsigned short* __restrict__ out0, unsigned short* __restrict__ out1,
    const float* __restrict__ rw)
{
  __shared__ unsigned short As[2][128 * 32];
  __shared__ unsigned short B0s[2][128 * 32];
  __shared__ unsigned short B1s[2][128 * 32];

  const int t = threadIdx.x;
  int bx, by;
  swizzle_xy(bx, by);
  const int m0 = by * 128, n0 = bx * 128;
  const int z = blockIdx.z;
  const unsigned short* Bb0 = B0b + (long long)z * sB;
  const unsigned short* Bb1 = B1b + (long long)z * sB;

  const int lane = t & 63, wave = t >> 6;
  const int wm = (wave >> 1) * 64, wn = (wave & 1) * 64;
  const int lrow = lane & 15, quad = lane >> 4;

  f32x4 acc0[4][4] = {}, acc1[4][4] = {};

  const int srow = lane >> 2;
  const int sko  = (lane & 3) * 8;
  const unsigned short* aRow0 = A   + (long long)(m0 + wave * 16       + srow) * HID_ + sko;
  const unsigned short* aRow1 = A   + (long long)(m0 + (wave + 4) * 16 + srow) * HID_ + sko;
  const unsigned short* gRow0 = Bb0 + (long long)(n0 + wave * 16       + srow) * HID_ + sko;
  const unsigned short* gRow1 = Bb0 + (long long)(n0 + (wave + 4) * 16 + srow) * HID_ + sko;
  const unsigned short* uRow0 = Bb1 + (long long)(n0 + wave * 16       + srow) * HID_ + sko;
  const unsigned short* uRow1 = Bb1 + (long long)(n0 + (wave + 4) * 16 + srow) * HID_ + sko;
  const int dst0 = (wave * 16) * 32, dst1 = ((wave + 4) * 16) * 32;

  gload16(aRow0, &As[0][dst0]);
  gload16(aRow1, &As[0][dst1]);
  gload16(gRow0, &B0s[0][dst0]);
  gload16(gRow1, &B0s[0][dst1]);
  gload16(uRow0, &B1s[0][dst0]);
  gload16(uRow1, &B1s[0][dst1]);

  int cur = 0;
  for (int kk = 0; kk < HID_; kk += 32, cur ^= 1) {
    __syncthreads();
    if (kk + 32 < HID_) {
      const int nxt = cur ^ 1, k2 = kk + 32;
      gload16(aRow0 + k2, &As[nxt][dst0]);
      gload16(aRow1 + k2, &As[nxt][dst1]);
      gload16(gRow0 + k2, &B0s[nxt][dst0]);
      gload16(gRow1 + k2, &B0s[nxt][dst1]);
      gload16(uRow0 + k2, &B1s[nxt][dst0]);
      gload16(uRow1 + k2, &B1s[nxt][dst1]);
    }
    bf16x8 af[4], b0[4], b1[4];
    #pragma unroll
    for (int i = 0; i < 4; ++i) {
      af[i] = *reinterpret_cast<const bf16x8*>(&As[cur][(wm + i * 16 + lrow) * 32 + quad * 8]);
      b0[i] = *reinterpret_cast<const bf16x8*>(&B0s[cur][(wn + i * 16 + lrow) * 32 + quad * 8]);
      b1[i] = *reinterpret_cast<const bf16x8*>(&B1s[cur][(wn + i * 16 + lrow) * 32 + quad * 8]);
    }
    #pragma unroll
    for (int i = 0; i < 4; ++i)
      #pragma unroll
      for (int j = 0; j < 4; ++j) {
        acc0[i][j] = __builtin_amdgcn_mfma_f32_16x16x32_bf16(af[i], b0[j], acc0[i][j], 0, 0, 0);
        acc1[i][j] = __builtin_amdgcn_mfma_f32_16x16x32_bf16(af[i], b1[j], acc1[i][j], 0, 0, 0);
      }
  }

  unsigned short* dsel = (z == 0) ? out0 : out1;   // GU path
  const int expert = zb + z;

  #pragma unroll
  for (int mi = 0; mi < 4; ++mi)
    #pragma unroll
    for (int r = 0; r < 4; ++r) {
      const int gm = m0 + wm + mi * 16 + quad * 4 + r;
      float rwv = 0.f;
      if (EPI2 == EPI2_GU) rwv = rw[(long long)gm * E_ + expert];
      #pragma unroll
      for (int ni = 0; ni < 4; ++ni) {
        const int gn = n0 + wn + ni * 16 + lrow;
        const float v0 = acc0[mi][ni][r];
        const float v1 = acc1[mi][ni][r];
        if (EPI2 == EPI2_QK) {
          const float eq = v0 > 0.f ? v0 + 1.f : __expf(v0);
          const float ek = v1 > 0.f ? v1 + 1.f : __expf(v1);
          out0[(long long)gm * HID_ + gn] = f32_to_bf16(eq);
          out1[(long long)gm * HID_ + gn] = f32_to_bf16(ek);
        } else {  // EPI2_GU
          const float sg = v0 / (1.f + __expf(-v0));      // silu(gate)
          dsel[(long long)gm * IM_ + gn] = f32_to_bf16(sg * v1 * rwv);
        }
      }
    }
}

// Paired down GEMM: out += gu0 @ d0^T + gu1 @ d1^T  (single accumulator,
// 4 staged matrices, 32 MFMA/barrier, 64 KiB LDS -> 2 blocks/CU).
__global__ __launch_bounds__(256) void gemm_down2_k(
    const unsigned short* __restrict__ A0,   // gu0 [M_][IM_]
    const unsigned short* __restrict__ A1,   // gu1 [M_][IM_]
    const unsigned short* __restrict__ B0,   // downT_e0 [HID_][IM_]
    const unsigned short* __restrict__ B1,   // downT_e1 [HID_][IM_]
    float* __restrict__ out)
{
  __shared__ unsigned short A0s[2][128 * 32];
  __shared__ unsigned short A1s[2][128 * 32];
  __shared__ unsigned short B0s[2][128 * 32];
  __shared__ unsigned short B1s[2][128 * 32];

  const int t = threadIdx.x;
  int bx, by;
  swizzle_xy(bx, by);
  const int m0 = by * 128, n0 = bx * 128;

  const int lane = t & 63, wave = t >> 6;
  const int wm = (wave >> 1) * 64, wn = (wave & 1) * 64;
  const int lrow = lane & 15, quad = lane >> 4;

  f32x4 acc[4][4] = {};

  const int srow = lane >> 2;
  const int sko  = (lane & 3) * 8;
  const unsigned short* a0r0 = A0 + (long long)(m0 + wave * 16       + srow) * IM_ + sko;
  const unsigned short* a0r1 = A0 + (long long)(m0 + (wave + 4) * 16 + srow) * IM_ + sko;
  const unsigned short* a1r0 = A1 + (long long)(m0 + wave * 16       + srow) * IM_ + sko;
  const unsigned short* a1r1 = A1 + (long long)(m0 + (wave + 4) * 16 + srow) * IM_ + sko;
  const unsigned short* b0r0 = B0 + (long long)(n0 + wave * 16       + srow) * IM_ + sko;
  const unsigned short* b0r1 = B0 + (long long)(n0 + (wave + 4) * 16 + srow) * IM_ + sko;
  const unsigned short* b1r0 = B1 + (long long)(n0 + wave * 16       + srow) * IM_ + sko;
  const unsigned short* b1r1 = B1 + (long long)(n0 + (wave + 4) * 16 + srow) * IM_ + sko;
  const int dst0 = (wave * 16) * 32, dst1 = ((wave + 4) * 16) * 32;

  gload16(a0r0, &A0s[0][dst0]);
  gload16(a0r1, &A0s[0][dst1]);
  gload16(a1r0, &A1s[0][dst0]);
  gload16(a1r1, &A1s[0][dst1]);
  gload16(b0r0, &B0s[0][dst0]);
  gload16(b0r1, &B0s[0][dst1]);
  gload16(b1r0, &B1s[0][dst0]);
  gload16(b1r1, &B1s[0][dst1]);

  int cur = 0;
  for (int kk = 0; kk < IM_; kk += 32, cur ^= 1) {
    __syncthreads();
    if (kk + 32 < IM_) {
      const int nxt = cur ^ 1, k2 = kk + 32;
      gload16(a0r0 + k2, &A0s[nxt][dst0]);
      gload16(a0r1 + k2, &A0s[nxt][dst1]);
      gload16(a1r0 + k2, &A1s[nxt][dst0]);
      gload16(a1r1 + k2, &A1s[nxt][dst1]);
      gload16(b0r0 + k2, &B0s[nxt][dst0]);
      gload16(b0r1 + k2, &B0s[nxt][dst1]);
      gload16(b1r0 + k2, &B1s[nxt][dst0]);
      gload16(b1r1 + k2, &B1s[nxt][dst1]);
    }
    bf16x8 a0f[4], a1f[4], b0f[4], b1f[4];
    #pragma unroll
    for (int i = 0; i < 4; ++i) {
      a0f[i] = *reinterpret_cast<const bf16x8*>(&A0s[cur][(wm + i * 16 + lrow) * 32 + quad * 8]);
      a1f[i] = *reinterpret_cast<const bf16x8*>(&A1s[cur][(wm + i * 16 + lrow) * 32 + quad * 8]);
      b0f[i] = *reinterpret_cast<const bf16x8*>(&B0s[cur][(wn + i * 16 + lrow) * 32 + quad * 8]);
      b1f[i] = *reinterpret_cast<const bf16x8*>(&B1s[cur][(wn + i * 16 + lrow) * 32 + quad * 8]);
    }
    #pragma unroll
    for (int i = 0; i < 4; ++i)
      #pragma unroll
      for (int j = 0; j < 4; ++j) {
        acc[i][j] = __builtin_amdgcn_mfma_f32_16x16x32_bf16(a0f[i], b0f[j], acc[i][j], 0, 0, 0);
        acc[i][j] = __builtin_amdgcn_mfma_f32_16x16x32_bf16(a1f[i], b1f[j], acc[i][j], 0, 0, 0);
      }
  }

  #pragma unroll
  for (int mi = 0; mi < 4; ++mi)
    #pragma unroll
    for (int ni = 0; ni < 4; ++ni)
      #pragma unroll
      for (int r = 0; r < 4; ++r) {
        const int gm = m0 + wm + mi * 16 + quad * 4 + r;
        const int gn = n0 + wn + ni * 16 + lrow;
        out[(long long)gm * HID_ + gn] += acc[mi][ni][r];
      }
}

// fp32 [R][C] -> bf16 [C][R]; z selects among 4 sources, dst stride R*C
__global__ void transpose_cast4_k(const float* s0, const float* s1,
                                  const float* s2, const float* s3,
                                  unsigned short* __restrict__ out, int R, int C)
{
  __shared__ float tile[32][33];
  const int z = blockIdx.z;
  const float* in = (z == 0) ? s0 : (z == 1) ? s1 : (z == 2) ? s2 : s3;
  unsigned short* o = out + (long long)z * R * C;
  const int c0 = blockIdx.x * 32, r0 = blockIdx.y * 32;
  const int tx = threadIdx.x, ty = threadIdx.y;
  #pragma unroll
  for (int i = 0; i < 32; i += 8)
    tile[ty + i][tx] = in[(long long)(r0 + ty + i) * C + c0 + tx];
  __syncthreads();
  #pragma unroll
  for (int i = 0; i < 32; i += 8)
    o[(long long)(c0 + ty + i) * R + r0 + tx] = f32_to_bf16(tile[tx][ty + i]);
}

// fp32 [R][C] -> bf16 [C][R]; z<4: srcA/dstA expert z; z>=4: srcB/dstB
__global__ void transpose_cast2x4_k(const float* __restrict__ sA,
                                    const float* __restrict__ sB,
                                    unsigned short* __restrict__ dA,
                                    unsigned short* __restrict__ dB,
                                    int R, int C)
{
  __shared__ float tile[32][33];
  const int z = blockIdx.z;
  const long long eo = (long long)(z & 3) * R * C;
  const float* in = ((z < 4) ? sA : sB) + eo;
  unsigned short* o = ((z < 4) ? dA : dB) + eo;
  const int c0 = blockIdx.x * 32, r0 = blockIdx.y * 32;
  const int tx = threadIdx.x, ty = threadIdx.y;
  #pragma unroll
  for (int i = 0; i < 32; i += 8)
    tile[ty + i][tx] = in[(long long)(r0 + ty + i) * C + c0 + tx];
  __syncthreads();
  #pragma unroll
  for (int i = 0; i < 32; i += 8)
    o[(long long)(c0 + ty + i) * R + r0 + tx] = f32_to_bf16(tile[tx][ty + i]);
}

// fp32 [R][C] -> bf16 [C][R], batched over z (single base, stride R*C)
__global__ void transpose_cast_k(const float* __restrict__ in,
                                 unsigned short* __restrict__ out, int R, int C)
{
  __shared__ float tile[32][33];
  const long long bo = (long long)blockIdx.z * R * C;
  const int c0 = blockIdx.x * 32, r0 = blockIdx.y * 32;
  const int tx = threadIdx.x, ty = threadIdx.y;
  #pragma unroll
  for (int i = 0; i < 32; i += 8)
    tile[ty + i][tx] = in[bo + (long long)(r0 + ty + i) * C + c0 + tx];
  __syncthreads();
  #pragma unroll
  for (int i = 0; i < 32; i += 8)
    out[bo + (long long)(c0 + ty + i) * R + r0 + tx] = f32_to_bf16(tile[tx][ty + i]);
}

// rmsnorm row (HID=1024) + weight + bf16 cast; one block per token
__global__ __launch_bounds__(256) void rmsnorm_cast_k(
    const float* __restrict__ x, const float* __restrict__ w,
    unsigned short* __restrict__ out)
{
  __shared__ float red[4];
  const int row = blockIdx.x, t = threadIdx.x;
  const float4 v = reinterpret_cast<const float4*>(x + (long long)row * HID_)[t];
  float ss = v.x * v.x + v.y * v.y + v.z * v.z + v.w * v.w;
  #pragma unroll
  for (int off = 32; off > 0; off >>= 1) ss += __shfl_down(ss, off, 64);
  if ((t & 63) == 0) red[t >> 6] = ss;
  __syncthreads();
  ss = red[0] + red[1] + red[2] + red[3];
  const float inv = rsqrtf(ss * (1.0f / HID_) + 1e-6f);
  const float4 wv = reinterpret_cast<const float4*>(w)[t];
  ushort4 o;
  o.x = f32_to_bf16(v.x * inv * wv.x);
  o.y = f32_to_bf16(v.y * inv * wv.y);
  o.z = f32_to_bf16(v.z * inv * wv.z);
  o.w = f32_to_bf16(v.w * inv * wv.w);
  reinterpret_cast<ushort4*>(out + (long long)row * HID_)[t] = o;
}

// softmax over a 2048-wide fp32 row; writes P bf16 IN PLACE over the row
__global__ __launch_bounds__(256) void softmax_rows_k(float* __restrict__ scores)
{
  __shared__ float red[4];
  const long long rbase = ((long long)blockIdx.y * S_ + blockIdx.x) * S_;
  float* row = scores + rbase;
  const int t = threadIdx.x;
  float v[8];
  #pragma unroll
  for (int i = 0; i < 8; ++i) v[i] = row[t + i * 256];
  float m = v[0];
  #pragma unroll
  for (int i = 1; i < 8; ++i) m = fmaxf(m, v[i]);
  #pragma unroll
  for (int off = 32; off > 0; off >>= 1) m = fmaxf(m, __shfl_down(m, off, 64));
  if ((t & 63) == 0) red[t >> 6] = m;
  __syncthreads();
  m = fmaxf(fmaxf(red[0], red[1]), fmaxf(red[2], red[3]));
  __syncthreads();
  float s = 0.f;
  #pragma unroll
  for (int i = 0; i < 8; ++i) { v[i] = __expf(v[i] - m); s += v[i]; }
  #pragma unroll
  for (int off = 32; off > 0; off >>= 1) s += __shfl_down(s, off, 64);
  if ((t & 63) == 0) red[t >> 6] = s;
  __syncthreads();
  const float inv = 1.0f / (red[0] + red[1] + red[2] + red[3]);
  unsigned short* prow = reinterpret_cast<unsigned short*>(scores) + rbase * 2;
  #pragma unroll
  for (int i = 0; i < 8; ++i) prow[t + i * 256] = f32_to_bf16(v[i] * inv);
}

// router: fp32 rms(h1)*ln2w @ router_w + b, softmax over E=4. One wave/token.
__global__ __launch_bounds__(256) void router_k(
    const float* __restrict__ h1, const float* __restrict__ ln2w,
    const float* __restrict__ rwgt, const float* __restrict__ rbias,
    float* __restrict__ rw)
{
  const int wv = threadIdx.x >> 6, lane = threadIdx.x & 63;
  const long long m = (long long)blockIdx.x * 4 + wv;
  const float* xr = h1 + m * HID_;
  float xv[16];
  float ss = 0.f;
  #pragma unroll
  for (int i = 0; i < 16; ++i) { xv[i] = xr[lane + i * 64]; ss += xv[i] * xv[i]; }
  #pragma unroll
  for (int off = 32; off > 0; off >>= 1) ss += __shfl_down(ss, off, 64);
  ss = __shfl(ss, 0, 64);
  const float inv = rsqrtf(ss * (1.0f / HID_) + 1e-6f);
  float l0 = 0, l1 = 0, l2 = 0, l3 = 0;
  #pragma unroll
  for (int i = 0; i < 16; ++i) {
    const int k = lane + i * 64;
    const float xn = xv[i] * inv * ln2w[k];
    const float4 wr = reinterpret_cast<const float4*>(rwgt)[k];
    l0 += xn * wr.x; l1 += xn * wr.y; l2 += xn * wr.z; l3 += xn * wr.w;
  }
  #pragma unroll
  for (int off = 32; off > 0; off >>= 1) {
    l0 += __shfl_down(l0, off, 64);
    l1 += __shfl_down(l1, off, 64);
    l2 += __shfl_down(l2, off, 64);
    l3 += __shfl_down(l3, off, 64);
  }
  if (lane == 0) {
    l0 += rbias[0]; l1 += rbias[1]; l2 += rbias[2]; l3 += rbias[3];
    const float mx = fmaxf(fmaxf(l0, l1), fmaxf(l2, l3));
    const float e0 = __expf(l0 - mx), e1 = __expf(l1 - mx);
    const float e2 = __expf(l2 - mx), e3 = __expf(l3 - mx);
    const float is = 1.0f / (e0 + e1 + e2 + e3);
    reinterpret_cast<float4*>(rw)[m] = make_float4(e0 * is, e1 * is, e2 * is, e3 * is);
  }
}

// balance loss: single block, deterministic
__global__ __launch_bounds__(256) void balance_k(const float* __restrict__ rw,
                                                 float* __restrict__ out_scalar)
{
  __shared__ float red[4];
  float acc = 0.f;
  for (int it = threadIdx.x; it < S_ * E_; it += 256) {
    const int s = it >> 2, e = it & 3;
    float mr = 0.f;
    #pragma unroll
    for (int b = 0; b < B_; ++b) mr += rw[((long long)b * S_ + s) * E_ + e];
    mr *= (1.0f / B_);
    const float d = mr - 1.0f / E_;
    acc += d * d;
  }
  #pragma unroll
  for (int off = 32; off > 0; off >>= 1) acc += __shfl_down(acc, off, 64);
  if ((threadIdx.x & 63) == 0) red[threadIdx.x >> 6] = acc;
  __syncthreads();
  if (threadIdx.x == 0)
    out_scalar[0] = (red[0] + red[1] + red[2] + red[3]) * (0.01f / (S_ * E_));
}

extern "C" void kernel_launch(void* const* d_in, const int* in_sizes, int n_in,
                              void* d_out, int out_size, void* d_ws, size_t ws_size,
                              hipStream_t stream)
{
  const float* hidden   = (const float*)d_in[0];
  const float* ln1w     = (const float*)d_in[1];
  const float* wq       = (const float*)d_in[2];
  const float* wk       = (const float*)d_in[3];
  const float* wv       = (const float*)d_in[4];
  const float* wo       = (const float*)d_in[5];
  const float* ln2w     = (const float*)d_in[6];
  const float* router_w = (const float*)d_in[7];
  const float* router_b = (const float*)d_in[8];
  const float* gate_w   = (const float*)d_in[9];
  const float* up_w     = (const float*)d_in[10];
  const float* down_w   = (const float*)d_in[11];
  float* out = (float*)d_out;   // h1 lives here; MoE accumulates in place

  char* ws = (char*)d_ws;
  size_t off = 0;
  auto carve = [&](size_t bytes) {
    off = (off + 255) & ~(size_t)255;
    char* p = ws + off;
    off += bytes;
    return p;
  };
  unsigned short* wqT   = (unsigned short*)carve((size_t)HID_ * HID_ * 2);  // 2 MiB
  unsigned short* wkT   = (unsigned short*)carve((size_t)HID_ * HID_ * 2);
  unsigned short* wvT   = (unsigned short*)carve((size_t)HID_ * HID_ * 2);
  unsigned short* woT   = (unsigned short*)carve((size_t)HID_ * HID_ * 2);
  unsigned short* x_bf  = (unsigned short*)carve((size_t)M_ * HID_ * 2);    // 16 MiB, reused as o_bf
  unsigned short* qb    = (unsigned short*)carve((size_t)M_ * HID_ * 2);    // 16 MiB, reused as x2_bf
  unsigned short* kb    = (unsigned short*)carve((size_t)M_ * HID_ * 2);    // 16 MiB \ gu0 (32 MiB)
  unsigned short* vT    = (unsigned short*)carve((size_t)M_ * HID_ * 2);    // 16 MiB /
  float*          rwbuf = (float*)carve((size_t)M_ * E_ * 4);               // 128 KiB
  char*           ubase = carve((size_t)NHG_ * S_ * S_ * 4);                // 64 MiB union
  const size_t base_bytes = off;
  float*          scores = (float*)ubase;
  unsigned short* gateT = (unsigned short*)(ubase);                          // 16 MiB
  unsigned short* upT   = (unsigned short*)(ubase + (size_t)16 * 1024 * 1024);
  unsigned short* downT = (unsigned short*)(ubase + (size_t)32 * 1024 * 1024);
  unsigned short* o_bf  = x_bf;
  unsigned short* x2_bf = qb;
  unsigned short* gu0   = kb;   // spans kb+vT = 32 MiB
  // paired mode needs a second 32 MiB gu buffer
  unsigned short* gu1   = (unsigned short*)carve((size_t)M_ * IM_ * 2);     // +32 MiB
  const bool paired = (ws_size >= off);
  (void)base_bytes;

  const dim3 blk256(256), blkT(32, 8);

  // 1) attention weights -> bf16 B^T (one dispatch, z=4)
  transpose_cast4_k<<<dim3(32, 32, 4), blkT, 0, stream>>>(wq, wk, wv, wo, wqT, HID_, HID_);

  // 2) x = bf16(rms(hidden, ln1_w))
  rmsnorm_cast_k<<<M_, blk256, 0, stream>>>(hidden, ln1w, x_bf);

  // 3) Q+K fused (dual-B, shared A staging, elu+1 epilogue); V transposed
  gemm_dual_k<EPI2_QK><<<dim3(8, 64, 1), blk256, 0, stream>>>(
      x_bf, wqT, wkT, 0, 0, qb, kb, nullptr);
  {
    EpiAux a{}; a.c_bf16 = vT;
    gemm_bf16k<EPI_VT><<<dim3(8, 64, 1), blk256, 0, stream>>>(
        x_bf, HID_, 0, 0, 0, wvT, HID_, 0, 0, 0, 0, 0, 0, HID_, a);
  }

  // 4) attention, NHG_=4 heads per group; scores slab reused per group
  for (int grp = 0; grp < 16 / NHG_; ++grp) {
    EpiAux as{}; as.c_f32 = scores; as.ldc = S_; as.strideCz = (long long)S_ * S_;
    gemm_bf16k<EPI_F32><<<dim3(16, 16, NHG_), blk256, 0, stream>>>(
        qb, HID_, (long long)S_ * HID_, HD_, grp * NHG_,
        kb, HID_, (long long)S_ * HID_, HD_, grp * NHG_,
        2, 3, 0, HD_, as);
    softmax_rows_k<<<dim3(S_, NHG_, 1), blk256, 0, stream>>>(scores);
    EpiAux ap{}; ap.c_bf16 = o_bf;
    gemm_bf16k<EPI_PV_O><<<dim3(2, 16, NHG_), blk256, 0, stream>>>(
        (const unsigned short*)scores, 2 * S_, (long long)S_ * 2 * S_, 0, 0,
        vT, S_, (long long)HD_ * S_, 0, grp * NHG_,
        0, 0, grp * NHG_, S_, ap);
  }

  // 5) MoE weights -> bf16 B^T into the now-dead scores slab
  transpose_cast2x4_k<<<dim3(64, 32, 8), blkT, 0, stream>>>(
      gate_w, up_w, gateT, upT, HID_, IM_);
  transpose_cast_k<<<dim3(32, 64, E_), blkT, 0, stream>>>(down_w, downT, IM_, HID_);

  // 6) h1 = hidden + O @ wo, written straight into d_out
  {
    EpiAux a{}; a.add_src = hidden; a.out2 = out;
    gemm_bf16k<EPI_WO><<<dim3(8, 64, 1), blk256, 0, stream>>>(
        o_bf, HID_, 0, 0, 0, woT, HID_, 0, 0, 0, 0, 0, 0, HID_, a);
  }

  // 7) x2 = bf16(rms(h1, ln2_w)); router (fp32); balance loss scalar
  rmsnorm_cast_k<<<M_, blk256, 0, stream>>>(out, ln2w, x2_bf);
  router_k<<<M_ / 4, blk256, 0, stream>>>(out, ln2w, router_w, router_b, rwbuf);
  balance_k<<<1, blk256, 0, stream>>>(rwbuf, out + (size_t)M_ * HID_);

  // 8) dense MoE, rw folded into gu
  const size_t wsz = (size_t)IM_ * HID_;
  if (paired) {
    for (int p = 0; p < 2; ++p) {
      const int e0 = 2 * p;
      // gu for experts e0,e0+1 in one z=2 dispatch (2048 blocks)
      gemm_dual_k<EPI2_GU><<<dim3(16, 64, 2), blk256, 0, stream>>>(
          x2_bf, gateT + (size_t)e0 * wsz, upT + (size_t)e0 * wsz,
          (long long)wsz, e0, gu0, gu1, rwbuf);
      // paired down: out += gu0 @ d_e0 + gu1 @ d_e1
      gemm_down2_k<<<dim3(8, 64, 1), blk256, 0, stream>>>(
          gu0, gu1, downT + (size_t)e0 * wsz, downT + (size_t)(e0 + 1) * wsz, out);
    }
  } else {
    for (int i = 0; i < E_; ++i) {
      gemm_dual_k<EPI2_GU><<<dim3(16, 64, 1), blk256, 0, stream>>>(
          x2_bf, gateT + (size_t)i * wsz, upT + (size_t)i * wsz,
          0, i, gu0, gu0, rwbuf);
      EpiAux ad{}; ad.out2 = out;
      gemm_bf16k<EPI_DOWN><<<dim3(8, 64, 1), blk256, 0, stream>>>(
          gu0, IM_, 0, 0, 0, downT + (size_t)i * wsz, IM_, 0, 0, 0,
          0, 0, 0, IM_, ad);
    }
  }
}

// Round 6
// 1119.264 us; speedup vs baseline: 1.2423x; 1.2423x over previous
//
#include <hip/hip_runtime.h>
#include <cstdint>
#include <cstddef>

// Problem constants (B,S,HID,NH,IM,E fixed by the reference)
#define B_    4
#define S_    2048
#define HID_  1024
#define NH_   4
#define HD_   256     // HID/NH
#define IM_   2048
#define E_    4
#define M_    8192    // B_*S_ tokens
#define NHG_  4       // heads per attention group

typedef __bf16 bf16x8 __attribute__((ext_vector_type(8)));
typedef float  f32x4  __attribute__((ext_vector_type(4)));

__device__ __forceinline__ unsigned short f32_to_bf16(float f) {
  unsigned int u = __float_as_uint(f);
  u += 0x7fffu + ((u >> 16) & 1u);   // round-to-nearest-even
  return (unsigned short)(u >> 16);
}

// async 16B global->LDS DMA (global_load_lds_dwordx4). LDS dest is
// wave-uniform base + lane*16 -> LDS layout contiguous in lane order.
__device__ __forceinline__ void gload16(const unsigned short* g, unsigned short* l) {
  __builtin_amdgcn_global_load_lds(
      (const __attribute__((address_space(1))) void*)g,
      (__attribute__((address_space(3))) void*)l, 16, 0, 0);
}

// XCD-aware swizzle: contiguous y-bands per XCD.
__device__ __forceinline__ void swizzle_xy(int& bx, int& by) {
  const int gx = gridDim.x, gy = gridDim.y;
  const int flat = blockIdx.x + blockIdx.y * gx;
  const int xcd = flat & 7, i = flat >> 3;
  const int rpx = gy >> 3;          // y-rows per XCD
  bx = i % gx;
  by = xcd * rpx + i / gx;
}

// ---------------- epilogue variants (generic single-B GEMM) ----------------
#define EPI_F32      0   // C fp32 (attention scores), batched via strideCz
#define EPI_VT       2   // write V^T [b][h][d][s] bf16
#define EPI_PV_O     3   // write attn O into [token][h*HD+n] bf16
#define EPI_WO       4   // out2 = add_src + acc  (h1 into d_out)
#define EPI_DOWN     5   // out2 += acc  (rw pre-folded into gu)

struct EpiAux {
  float* c_f32;
  unsigned short* c_bf16;
  const float* add_src;       // hidden (WO)
  float* out2;                // d_out (WO/DOWN)
  long long strideCz;
  int ldc;
};

// Generic batched GEMM: C[z] = A[z] (MxK, row-major, lda) @ B[z]^T.
// 128x128 tile, BK=32, 4 waves x (4x4) 16x16x32 bf16 MFMA fragments.
// Double-buffered LDS, one-iteration-ahead async global_load_lds prefetch.
template<int EPI>
__global__ __launch_bounds__(256) void gemm_bf16k(
    const unsigned short* __restrict__ A, int lda, long long sAo, long long sAi, int zbA,
    const unsigned short* __restrict__ B, int ldb, long long sBo, long long sBi, int zbB,
    int zshift, int zmask, int zbC, int K, EpiAux aux)
{
  __shared__ unsigned short As[2][128 * 32];
  __shared__ unsigned short Bs[2][128 * 32];

  const int t = threadIdx.x;
  int bx, by;
  swizzle_xy(bx, by);
  const int m0 = by * 128, n0 = bx * 128;
  const int z  = blockIdx.z;
  const int zA = z + zbA, zB = z + zbB, zC = z + zbC;
  const unsigned short* Ab = A + (long long)(zA >> zshift) * sAo + (long long)(zA & zmask) * sAi;
  const unsigned short* Bb = B + (long long)(zB >> zshift) * sBo + (long long)(zB & zmask) * sBi;

  const int lane = t & 63, wave = t >> 6;
  const int wm = (wave >> 1) * 64, wn = (wave & 1) * 64;
  const int lrow = lane & 15, quad = lane >> 4;

  f32x4 acc[4][4] = {};

  const int srow = lane >> 2;         // 0..15
  const int sko  = (lane & 3) * 8;    // k-elem 0/8/16/24
  const unsigned short* aRow0 = Ab + (long long)(m0 + wave * 16       + srow) * lda + sko;
  const unsigned short* aRow1 = Ab + (long long)(m0 + (wave + 4) * 16 + srow) * lda + sko;
  const unsigned short* bRow0 = Bb + (long long)(n0 + wave * 16       + srow) * ldb + sko;
  const unsigned short* bRow1 = Bb + (long long)(n0 + (wave + 4) * 16 + srow) * ldb + sko;
  const int dst0 = (wave * 16) * 32, dst1 = ((wave + 4) * 16) * 32;

  gload16(aRow0, &As[0][dst0]);
  gload16(aRow1, &As[0][dst1]);
  gload16(bRow0, &Bs[0][dst0]);
  gload16(bRow1, &Bs[0][dst1]);

  int cur = 0;
  for (int kk = 0; kk < K; kk += 32, cur ^= 1) {
    __syncthreads();
    if (kk + 32 < K) {
      const int nxt = cur ^ 1, k2 = kk + 32;
      gload16(aRow0 + k2, &As[nxt][dst0]);
      gload16(aRow1 + k2, &As[nxt][dst1]);
      gload16(bRow0 + k2, &Bs[nxt][dst0]);
      gload16(bRow1 + k2, &Bs[nxt][dst1]);
    }
    bf16x8 af[4], bfr[4];
    #pragma unroll
    for (int i = 0; i < 4; ++i) {
      af[i]  = *reinterpret_cast<const bf16x8*>(&As[cur][(wm + i * 16 + lrow) * 32 + quad * 8]);
      bfr[i] = *reinterpret_cast<const bf16x8*>(&Bs[cur][(wn + i * 16 + lrow) * 32 + quad * 8]);
    }
    #pragma unroll
    for (int i = 0; i < 4; ++i)
      #pragma unroll
      for (int j = 0; j < 4; ++j)
        acc[i][j] = __builtin_amdgcn_mfma_f32_16x16x32_bf16(af[i], bfr[j], acc[i][j], 0, 0, 0);
  }

  // epilogue: D row = quad*4+r, col = lane&15
  #pragma unroll
  for (int mi = 0; mi < 4; ++mi) {
    #pragma unroll
    for (int ni = 0; ni < 4; ++ni) {
      #pragma unroll
      for (int r = 0; r < 4; ++r) {
        const int gm = m0 + wm + mi * 16 + quad * 4 + r;
        const int gn = n0 + wn + ni * 16 + lrow;
        const float val = acc[mi][ni][r];
        if (EPI == EPI_F32) {
          aux.c_f32[(long long)zC * aux.strideCz + (long long)gm * aux.ldc + gn] = val;
        } else if (EPI == EPI_VT) {
          const int b = gm >> 11, s = gm & (S_ - 1);
          const int h = gn >> 8, d = gn & (HD_ - 1);
          aux.c_bf16[((long long)(b * NH_ + h) * HD_ + d) * S_ + s] = f32_to_bf16(val);
        } else if (EPI == EPI_PV_O) {
          const int b = zC >> 2, h = zC & (NH_ - 1);
          aux.c_bf16[((long long)(b * S_ + gm)) * HID_ + h * HD_ + gn] = f32_to_bf16(val);
        } else if (EPI == EPI_WO) {
          const long long idx = (long long)gm * HID_ + gn;
          aux.out2[idx] = val + aux.add_src[idx];
        } else if (EPI == EPI_DOWN) {
          const long long idx = (long long)gm * HID_ + gn;
          aux.out2[idx] += val;
        }
      }
    }
  }
}

// ---- dual-B GEMM (shared A staging, two accumulator sets, 32 MFMA/barrier)
// __launch_bounds__(256, 2) is LOAD-BEARING: without the 2-waves/EU floor the
// allocator uses ~280 regs/wave (incl AGPR) -> 1 block/CU -> r5's 472 TF
// collapse. With it: ~96 VGPR + 128 AGPR -> 2 blocks/CU -> 805 TF (r4).
#define EPI2_QK 0   // out0 = bf16(elu(accq)+1), out1 = bf16(elu(acck)+1)
#define EPI2_GU 1   // out0 = bf16(silu(g)*u*rw[token][zb]), ldc=IM_

template<int EPI2>
__global__ __launch_bounds__(256, 2) void gemm_dual_k(
    const unsigned short* __restrict__ A,      // [M_][HID_]
    const unsigned short* __restrict__ B0b,    // B0 [*][HID_]
    const unsigned short* __restrict__ B1b,    // B1 [*][HID_]
    int zb,
    unsigned short* __restrict__ out0, unsigned short* __restrict__ out1,
    const float* __restrict__ rw)
{
  __shared__ unsigned short As[2][128 * 32];
  __shared__ unsigned short B0s[2][128 * 32];
  __shared__ unsigned short B1s[2][128 * 32];

  const int t = threadIdx.x;
  int bx, by;
  swizzle_xy(bx, by);
  const int m0 = by * 128, n0 = bx * 128;

  const int lane = t & 63, wave = t >> 6;
  const int wm = (wave >> 1) * 64, wn = (wave & 1) * 64;
  const int lrow = lane & 15, quad = lane >> 4;

  f32x4 acc0[4][4] = {}, acc1[4][4] = {};

  const int srow = lane >> 2;
  const int sko  = (lane & 3) * 8;
  const unsigned short* aRow0 = A   + (long long)(m0 + wave * 16       + srow) * HID_ + sko;
  const unsigned short* aRow1 = A   + (long long)(m0 + (wave + 4) * 16 + srow) * HID_ + sko;
  const unsigned short* gRow0 = B0b + (long long)(n0 + wave * 16       + srow) * HID_ + sko;
  const unsigned short* gRow1 = B0b + (long long)(n0 + (wave + 4) * 16 + srow) * HID_ + sko;
  const unsigned short* uRow0 = B1b + (long long)(n0 + wave * 16       + srow) * HID_ + sko;
  const unsigned short* uRow1 = B1b + (long long)(n0 + (wave + 4) * 16 + srow) * HID_ + sko;
  const int dst0 = (wave * 16) * 32, dst1 = ((wave + 4) * 16) * 32;

  gload16(aRow0, &As[0][dst0]);
  gload16(aRow1, &As[0][dst1]);
  gload16(gRow0, &B0s[0][dst0]);
  gload16(gRow1, &B0s[0][dst1]);
  gload16(uRow0, &B1s[0][dst0]);
  gload16(uRow1, &B1s[0][dst1]);

  int cur = 0;
  for (int kk = 0; kk < HID_; kk += 32, cur ^= 1) {
    __syncthreads();
    if (kk + 32 < HID_) {
      const int nxt = cur ^ 1, k2 = kk + 32;
      gload16(aRow0 + k2, &As[nxt][dst0]);
      gload16(aRow1 + k2, &As[nxt][dst1]);
      gload16(gRow0 + k2, &B0s[nxt][dst0]);
      gload16(gRow1 + k2, &B0s[nxt][dst1]);
      gload16(uRow0 + k2, &B1s[nxt][dst0]);
      gload16(uRow1 + k2, &B1s[nxt][dst1]);
    }
    bf16x8 af[4], b0[4], b1[4];
    #pragma unroll
    for (int i = 0; i < 4; ++i) {
      af[i] = *reinterpret_cast<const bf16x8*>(&As[cur][(wm + i * 16 + lrow) * 32 + quad * 8]);
      b0[i] = *reinterpret_cast<const bf16x8*>(&B0s[cur][(wn + i * 16 + lrow) * 32 + quad * 8]);
      b1[i] = *reinterpret_cast<const bf16x8*>(&B1s[cur][(wn + i * 16 + lrow) * 32 + quad * 8]);
    }
    #pragma unroll
    for (int i = 0; i < 4; ++i)
      #pragma unroll
      for (int j = 0; j < 4; ++j) {
        acc0[i][j] = __builtin_amdgcn_mfma_f32_16x16x32_bf16(af[i], b0[j], acc0[i][j], 0, 0, 0);
        acc1[i][j] = __builtin_amdgcn_mfma_f32_16x16x32_bf16(af[i], b1[j], acc1[i][j], 0, 0, 0);
      }
  }

  #pragma unroll
  for (int mi = 0; mi < 4; ++mi)
    #pragma unroll
    for (int r = 0; r < 4; ++r) {
      const int gm = m0 + wm + mi * 16 + quad * 4 + r;
      float rwv = 0.f;
      if (EPI2 == EPI2_GU) rwv = rw[(long long)gm * E_ + zb];
      #pragma unroll
      for (int ni = 0; ni < 4; ++ni) {
        const int gn = n0 + wn + ni * 16 + lrow;
        const float v0 = acc0[mi][ni][r];
        const float v1 = acc1[mi][ni][r];
        if (EPI2 == EPI2_QK) {
          const float eq = v0 > 0.f ? v0 + 1.f : __expf(v0);
          const float ek = v1 > 0.f ? v1 + 1.f : __expf(v1);
          out0[(long long)gm * HID_ + gn] = f32_to_bf16(eq);
          out1[(long long)gm * HID_ + gn] = f32_to_bf16(ek);
        } else {  // EPI2_GU
          const float sg = v0 / (1.f + __expf(-v0));      // silu(gate)
          out0[(long long)gm * IM_ + gn] = f32_to_bf16(sg * v1 * rwv);
        }
      }
    }
}

// Paired down GEMM: out += gu0 @ d0^T + gu1 @ d1^T  (single accumulator,
// 4 staged matrices, 32 MFMA/barrier, 64 KiB LDS -> 2 blocks/CU).
__global__ __launch_bounds__(256, 2) void gemm_down2_k(
    const unsigned short* __restrict__ A0,   // gu0 [M_][IM_]
    const unsigned short* __restrict__ A1,   // gu1 [M_][IM_]
    const unsigned short* __restrict__ B0,   // downT_e0 [HID_][IM_]
    const unsigned short* __restrict__ B1,   // downT_e1 [HID_][IM_]
    float* __restrict__ out)
{
  __shared__ unsigned short A0s[2][128 * 32];
  __shared__ unsigned short A1s[2][128 * 32];
  __shared__ unsigned short B0s[2][128 * 32];
  __shared__ unsigned short B1s[2][128 * 32];

  const int t = threadIdx.x;
  int bx, by;
  swizzle_xy(bx, by);
  const int m0 = by * 128, n0 = bx * 128;

  const int lane = t & 63, wave = t >> 6;
  const int wm = (wave >> 1) * 64, wn = (wave & 1) * 64;
  const int lrow = lane & 15, quad = lane >> 4;

  f32x4 acc[4][4] = {};

  const int srow = lane >> 2;
  const int sko  = (lane & 3) * 8;
  const unsigned short* a0r0 = A0 + (long long)(m0 + wave * 16       + srow) * IM_ + sko;
  const unsigned short* a0r1 = A0 + (long long)(m0 + (wave + 4) * 16 + srow) * IM_ + sko;
  const unsigned short* a1r0 = A1 + (long long)(m0 + wave * 16       + srow) * IM_ + sko;
  const unsigned short* a1r1 = A1 + (long long)(m0 + (wave + 4) * 16 + srow) * IM_ + sko;
  const unsigned short* b0r0 = B0 + (long long)(n0 + wave * 16       + srow) * IM_ + sko;
  const unsigned short* b0r1 = B0 + (long long)(n0 + (wave + 4) * 16 + srow) * IM_ + sko;
  const unsigned short* b1r0 = B1 + (long long)(n0 + wave * 16       + srow) * IM_ + sko;
  const unsigned short* b1r1 = B1 + (long long)(n0 + (wave + 4) * 16 + srow) * IM_ + sko;
  const int dst0 = (wave * 16) * 32, dst1 = ((wave + 4) * 16) * 32;

  gload16(a0r0, &A0s[0][dst0]);
  gload16(a0r1, &A0s[0][dst1]);
  gload16(a1r0, &A1s[0][dst0]);
  gload16(a1r1, &A1s[0][dst1]);
  gload16(b0r0, &B0s[0][dst0]);
  gload16(b0r1, &B0s[0][dst1]);
  gload16(b1r0, &B1s[0][dst0]);
  gload16(b1r1, &B1s[0][dst1]);

  int cur = 0;
  for (int kk = 0; kk < IM_; kk += 32, cur ^= 1) {
    __syncthreads();
    if (kk + 32 < IM_) {
      const int nxt = cur ^ 1, k2 = kk + 32;
      gload16(a0r0 + k2, &A0s[nxt][dst0]);
      gload16(a0r1 + k2, &A0s[nxt][dst1]);
      gload16(a1r0 + k2, &A1s[nxt][dst0]);
      gload16(a1r1 + k2, &A1s[nxt][dst1]);
      gload16(b0r0 + k2, &B0s[nxt][dst0]);
      gload16(b0r1 + k2, &B0s[nxt][dst1]);
      gload16(b1r0 + k2, &B1s[nxt][dst0]);
      gload16(b1r1 + k2, &B1s[nxt][dst1]);
    }
    bf16x8 a0f[4], a1f[4], b0f[4], b1f[4];
    #pragma unroll
    for (int i = 0; i < 4; ++i) {
      a0f[i] = *reinterpret_cast<const bf16x8*>(&A0s[cur][(wm + i * 16 + lrow) * 32 + quad * 8]);
      a1f[i] = *reinterpret_cast<const bf16x8*>(&A1s[cur][(wm + i * 16 + lrow) * 32 + quad * 8]);
      b0f[i] = *reinterpret_cast<const bf16x8*>(&B0s[cur][(wn + i * 16 + lrow) * 32 + quad * 8]);
      b1f[i] = *reinterpret_cast<const bf16x8*>(&B1s[cur][(wn + i * 16 + lrow) * 32 + quad * 8]);
    }
    #pragma unroll
    for (int i = 0; i < 4; ++i)
      #pragma unroll
      for (int j = 0; j < 4; ++j) {
        acc[i][j] = __builtin_amdgcn_mfma_f32_16x16x32_bf16(a0f[i], b0f[j], acc[i][j], 0, 0, 0);
        acc[i][j] = __builtin_amdgcn_mfma_f32_16x16x32_bf16(a1f[i], b1f[j], acc[i][j], 0, 0, 0);
      }
  }

  #pragma unroll
  for (int mi = 0; mi < 4; ++mi)
    #pragma unroll
    for (int ni = 0; ni < 4; ++ni)
      #pragma unroll
      for (int r = 0; r < 4; ++r) {
        const int gm = m0 + wm + mi * 16 + quad * 4 + r;
        const int gn = n0 + wn + ni * 16 + lrow;
        out[(long long)gm * HID_ + gn] += acc[mi][ni][r];
      }
}

// fp32 [R][C] -> bf16 [C][R]; z selects among 4 sources, dst stride R*C
__global__ void transpose_cast4_k(const float* s0, const float* s1,
                                  const float* s2, const float* s3,
                                  unsigned short* __restrict__ out, int R, int C)
{
  __shared__ float tile[32][33];
  const int z = blockIdx.z;
  const float* in = (z == 0) ? s0 : (z == 1) ? s1 : (z == 2) ? s2 : s3;
  unsigned short* o = out + (long long)z * R * C;
  const int c0 = blockIdx.x * 32, r0 = blockIdx.y * 32;
  const int tx = threadIdx.x, ty = threadIdx.y;
  #pragma unroll
  for (int i = 0; i < 32; i += 8)
    tile[ty + i][tx] = in[(long long)(r0 + ty + i) * C + c0 + tx];
  __syncthreads();
  #pragma unroll
  for (int i = 0; i < 32; i += 8)
    o[(long long)(c0 + ty + i) * R + r0 + tx] = f32_to_bf16(tile[tx][ty + i]);
}

// fp32 [R][C] -> bf16 [C][R]; z<4: srcA/dstA expert z; z>=4: srcB/dstB
__global__ void transpose_cast2x4_k(const float* __restrict__ sA,
                                    const float* __restrict__ sB,
                                    unsigned short* __restrict__ dA,
                                    unsigned short* __restrict__ dB,
                                    int R, int C)
{
  __shared__ float tile[32][33];
  const int z = blockIdx.z;
  const long long eo = (long long)(z & 3) * R * C;
  const float* in = ((z < 4) ? sA : sB) + eo;
  unsigned short* o = ((z < 4) ? dA : dB) + eo;
  const int c0 = blockIdx.x * 32, r0 = blockIdx.y * 32;
  const int tx = threadIdx.x, ty = threadIdx.y;
  #pragma unroll
  for (int i = 0; i < 32; i += 8)
    tile[ty + i][tx] = in[(long long)(r0 + ty + i) * C + c0 + tx];
  __syncthreads();
  #pragma unroll
  for (int i = 0; i < 32; i += 8)
    o[(long long)(c0 + ty + i) * R + r0 + tx] = f32_to_bf16(tile[tx][ty + i]);
}

// fp32 [R][C] -> bf16 [C][R], batched over z (single base, stride R*C)
__global__ void transpose_cast_k(const float* __restrict__ in,
                                 unsigned short* __restrict__ out, int R, int C)
{
  __shared__ float tile[32][33];
  const long long bo = (long long)blockIdx.z * R * C;
  const int c0 = blockIdx.x * 32, r0 = blockIdx.y * 32;
  const int tx = threadIdx.x, ty = threadIdx.y;
  #pragma unroll
  for (int i = 0; i < 32; i += 8)
    tile[ty + i][tx] = in[bo + (long long)(r0 + ty + i) * C + c0 + tx];
  __syncthreads();
  #pragma unroll
  for (int i = 0; i < 32; i += 8)
    out[bo + (long long)(c0 + ty + i) * R + r0 + tx] = f32_to_bf16(tile[tx][ty + i]);
}

// rmsnorm row (HID=1024) + weight + bf16 cast; one block per token
__global__ __launch_bounds__(256) void rmsnorm_cast_k(
    const float* __restrict__ x, const float* __restrict__ w,
    unsigned short* __restrict__ out)
{
  __shared__ float red[4];
  const int row = blockIdx.x, t = threadIdx.x;
  const float4 v = reinterpret_cast<const float4*>(x + (long long)row * HID_)[t];
  float ss = v.x * v.x + v.y * v.y + v.z * v.z + v.w * v.w;
  #pragma unroll
  for (int off = 32; off > 0; off >>= 1) ss += __shfl_down(ss, off, 64);
  if ((t & 63) == 0) red[t >> 6] = ss;
  __syncthreads();
  ss = red[0] + red[1] + red[2] + red[3];
  const float inv = rsqrtf(ss * (1.0f / HID_) + 1e-6f);
  const float4 wv = reinterpret_cast<const float4*>(w)[t];
  ushort4 o;
  o.x = f32_to_bf16(v.x * inv * wv.x);
  o.y = f32_to_bf16(v.y * inv * wv.y);
  o.z = f32_to_bf16(v.z * inv * wv.z);
  o.w = f32_to_bf16(v.w * inv * wv.w);
  reinterpret_cast<ushort4*>(out + (long long)row * HID_)[t] = o;
}

// softmax over a 2048-wide fp32 row; writes P bf16 IN PLACE over the row
__global__ __launch_bounds__(256) void softmax_rows_k(float* __restrict__ scores)
{
  __shared__ float red[4];
  const long long rbase = ((long long)blockIdx.y * S_ + blockIdx.x) * S_;
  float* row = scores + rbase;
  const int t = threadIdx.x;
  float v[8];
  #pragma unroll
  for (int i = 0; i < 8; ++i) v[i] = row[t + i * 256];
  float m = v[0];
  #pragma unroll
  for (int i = 1; i < 8; ++i) m = fmaxf(m, v[i]);
  #pragma unroll
  for (int off = 32; off > 0; off >>= 1) m = fmaxf(m, __shfl_down(m, off, 64));
  if ((t & 63) == 0) red[t >> 6] = m;
  __syncthreads();
  m = fmaxf(fmaxf(red[0], red[1]), fmaxf(red[2], red[3]));
  __syncthreads();
  float s = 0.f;
  #pragma unroll
  for (int i = 0; i < 8; ++i) { v[i] = __expf(v[i] - m); s += v[i]; }
  #pragma unroll
  for (int off = 32; off > 0; off >>= 1) s += __shfl_down(s, off, 64);
  if ((t & 63) == 0) red[t >> 6] = s;
  __syncthreads();
  const float inv = 1.0f / (red[0] + red[1] + red[2] + red[3]);
  unsigned short* prow = reinterpret_cast<unsigned short*>(scores) + rbase * 2;
  #pragma unroll
  for (int i = 0; i < 8; ++i) prow[t + i * 256] = f32_to_bf16(v[i] * inv);
}

// router: fp32 rms(h1)*ln2w @ router_w + b, softmax over E=4. One wave/token.
__global__ __launch_bounds__(256) void router_k(
    const float* __restrict__ h1, const float* __restrict__ ln2w,
    const float* __restrict__ rwgt, const float* __restrict__ rbias,
    float* __restrict__ rw)
{
  const int wv = threadIdx.x >> 6, lane = threadIdx.x & 63;
  const long long m = (long long)blockIdx.x * 4 + wv;
  const float* xr = h1 + m * HID_;
  float xv[16];
  float ss = 0.f;
  #pragma unroll
  for (int i = 0; i < 16; ++i) { xv[i] = xr[lane + i * 64]; ss += xv[i] * xv[i]; }
  #pragma unroll
  for (int off = 32; off > 0; off >>= 1) ss += __shfl_down(ss, off, 64);
  ss = __shfl(ss, 0, 64);
  const float inv = rsqrtf(ss * (1.0f / HID_) + 1e-6f);
  float l0 = 0, l1 = 0, l2 = 0, l3 = 0;
  #pragma unroll
  for (int i = 0; i < 16; ++i) {
    const int k = lane + i * 64;
    const float xn = xv[i] * inv * ln2w[k];
    const float4 wr = reinterpret_cast<const float4*>(rwgt)[k];
    l0 += xn * wr.x; l1 += xn * wr.y; l2 += xn * wr.z; l3 += xn * wr.w;
  }
  #pragma unroll
  for (int off = 32; off > 0; off >>= 1) {
    l0 += __shfl_down(l0, off, 64);
    l1 += __shfl_down(l1, off, 64);
    l2 += __shfl_down(l2, off, 64);
    l3 += __shfl_down(l3, off, 64);
  }
  if (lane == 0) {
    l0 += rbias[0]; l1 += rbias[1]; l2 += rbias[2]; l3 += rbias[3];
    const float mx = fmaxf(fmaxf(l0, l1), fmaxf(l2, l3));
    const float e0 = __expf(l0 - mx), e1 = __expf(l1 - mx);
    const float e2 = __expf(l2 - mx), e3 = __expf(l3 - mx);
    const float is = 1.0f / (e0 + e1 + e2 + e3);
    reinterpret_cast<float4*>(rw)[m] = make_float4(e0 * is, e1 * is, e2 * is, e3 * is);
  }
}

// balance loss: single block, deterministic
__global__ __launch_bounds__(256) void balance_k(const float* __restrict__ rw,
                                                 float* __restrict__ out_scalar)
{
  __shared__ float red[4];
  float acc = 0.f;
  for (int it = threadIdx.x; it < S_ * E_; it += 256) {
    const int s = it >> 2, e = it & 3;
    float mr = 0.f;
    #pragma unroll
    for (int b = 0; b < B_; ++b) mr += rw[((long long)b * S_ + s) * E_ + e];
    mr *= (1.0f / B_);
    const float d = mr - 1.0f / E_;
    acc += d * d;
  }
  #pragma unroll
  for (int off = 32; off > 0; off >>= 1) acc += __shfl_down(acc, off, 64);
  if ((threadIdx.x & 63) == 0) red[threadIdx.x >> 6] = acc;
  __syncthreads();
  if (threadIdx.x == 0)
    out_scalar[0] = (red[0] + red[1] + red[2] + red[3]) * (0.01f / (S_ * E_));
}

extern "C" void kernel_launch(void* const* d_in, const int* in_sizes, int n_in,
                              void* d_out, int out_size, void* d_ws, size_t ws_size,
                              hipStream_t stream)
{
  const float* hidden   = (const float*)d_in[0];
  const float* ln1w     = (const float*)d_in[1];
  const float* wq       = (const float*)d_in[2];
  const float* wk       = (const float*)d_in[3];
  const float* wv       = (const float*)d_in[4];
  const float* wo       = (const float*)d_in[5];
  const float* ln2w     = (const float*)d_in[6];
  const float* router_w = (const float*)d_in[7];
  const float* router_b = (const float*)d_in[8];
  const float* gate_w   = (const float*)d_in[9];
  const float* up_w     = (const float*)d_in[10];
  const float* down_w   = (const float*)d_in[11];
  float* out = (float*)d_out;   // h1 lives here; MoE accumulates in place

  char* ws = (char*)d_ws;
  size_t off = 0;
  auto carve = [&](size_t bytes) {
    off = (off + 255) & ~(size_t)255;
    char* p = ws + off;
    off += bytes;
    return p;
  };
  unsigned short* wqT   = (unsigned short*)carve((size_t)HID_ * HID_ * 2);  // 2 MiB
  unsigned short* wkT   = (unsigned short*)carve((size_t)HID_ * HID_ * 2);
  unsigned short* wvT   = (unsigned short*)carve((size_t)HID_ * HID_ * 2);
  unsigned short* woT   = (unsigned short*)carve((size_t)HID_ * HID_ * 2);
  unsigned short* x_bf  = (unsigned short*)carve((size_t)M_ * HID_ * 2);    // 16 MiB, reused as o_bf
  unsigned short* qb    = (unsigned short*)carve((size_t)M_ * HID_ * 2);    // 16 MiB, reused as x2_bf
  unsigned short* kb    = (unsigned short*)carve((size_t)M_ * HID_ * 2);    // 16 MiB \ gu0 (32 MiB)
  unsigned short* vT    = (unsigned short*)carve((size_t)M_ * HID_ * 2);    // 16 MiB /
  float*          rwbuf = (float*)carve((size_t)M_ * E_ * 4);               // 128 KiB
  char*           ubase = carve((size_t)NHG_ * S_ * S_ * 4);                // 64 MiB union
  float*          scores = (float*)ubase;
  unsigned short* gateT = (unsigned short*)(ubase);                          // 16 MiB
  unsigned short* upT   = (unsigned short*)(ubase + (size_t)16 * 1024 * 1024);
  unsigned short* downT = (unsigned short*)(ubase + (size_t)32 * 1024 * 1024);
  unsigned short* o_bf  = x_bf;
  unsigned short* x2_bf = qb;
  unsigned short* gu0   = kb;   // spans kb+vT = 32 MiB
  // paired down needs a second 32 MiB gu buffer
  unsigned short* gu1   = (unsigned short*)carve((size_t)M_ * IM_ * 2);     // +32 MiB
  const bool paired = (ws_size >= off);

  const dim3 blk256(256), blkT(32, 8);

  // 1) attention weights -> bf16 B^T (one dispatch, z=4)
  transpose_cast4_k<<<dim3(32, 32, 4), blkT, 0, stream>>>(wq, wk, wv, wo, wqT, HID_, HID_);

  // 2) x = bf16(rms(hidden, ln1_w))
  rmsnorm_cast_k<<<M_, blk256, 0, stream>>>(hidden, ln1w, x_bf);

  // 3) Q+K fused (dual-B, shared A staging, elu+1 epilogue); V transposed
  gemm_dual_k<EPI2_QK><<<dim3(8, 64, 1), blk256, 0, stream>>>(
      x_bf, wqT, wkT, 0, qb, kb, nullptr);
  {
    EpiAux a{}; a.c_bf16 = vT;
    gemm_bf16k<EPI_VT><<<dim3(8, 64, 1), blk256, 0, stream>>>(
        x_bf, HID_, 0, 0, 0, wvT, HID_, 0, 0, 0, 0, 0, 0, HID_, a);
  }

  // 4) attention, NHG_=4 heads per group; scores slab reused per group
  for (int grp = 0; grp < 16 / NHG_; ++grp) {
    EpiAux as{}; as.c_f32 = scores; as.ldc = S_; as.strideCz = (long long)S_ * S_;
    gemm_bf16k<EPI_F32><<<dim3(16, 16, NHG_), blk256, 0, stream>>>(
        qb, HID_, (long long)S_ * HID_, HD_, grp * NHG_,
        kb, HID_, (long long)S_ * HID_, HD_, grp * NHG_,
        2, 3, 0, HD_, as);
    softmax_rows_k<<<dim3(S_, NHG_, 1), blk256, 0, stream>>>(scores);
    EpiAux ap{}; ap.c_bf16 = o_bf;
    gemm_bf16k<EPI_PV_O><<<dim3(2, 16, NHG_), blk256, 0, stream>>>(
        (const unsigned short*)scores, 2 * S_, (long long)S_ * 2 * S_, 0, 0,
        vT, S_, (long long)HD_ * S_, 0, grp * NHG_,
        0, 0, grp * NHG_, S_, ap);
  }

  // 5) MoE weights -> bf16 B^T into the now-dead scores slab
  transpose_cast2x4_k<<<dim3(64, 32, 8), blkT, 0, stream>>>(
      gate_w, up_w, gateT, upT, HID_, IM_);
  transpose_cast_k<<<dim3(32, 64, E_), blkT, 0, stream>>>(down_w, downT, IM_, HID_);

  // 6) h1 = hidden + O @ wo, written straight into d_out
  {
    EpiAux a{}; a.add_src = hidden; a.out2 = out;
    gemm_bf16k<EPI_WO><<<dim3(8, 64, 1), blk256, 0, stream>>>(
        o_bf, HID_, 0, 0, 0, woT, HID_, 0, 0, 0, 0, 0, 0, HID_, a);
  }

  // 7) x2 = bf16(rms(h1, ln2_w)); router (fp32); balance loss scalar
  rmsnorm_cast_k<<<M_, blk256, 0, stream>>>(out, ln2w, x2_bf);
  router_k<<<M_ / 4, blk256, 0, stream>>>(out, ln2w, router_w, router_b, rwbuf);
  balance_k<<<1, blk256, 0, stream>>>(rwbuf, out + (size_t)M_ * HID_);

  // 8) dense MoE, rw folded into gu; per-expert gu (r4's proven shape),
  //    paired down when the second gu buffer fits.
  const size_t wsz = (size_t)IM_ * HID_;
  if (paired) {
    for (int p = 0; p < 2; ++p) {
      const int e0 = 2 * p, e1 = e0 + 1;
      gemm_dual_k<EPI2_GU><<<dim3(16, 64, 1), blk256, 0, stream>>>(
          x2_bf, gateT + (size_t)e0 * wsz, upT + (size_t)e0 * wsz, e0, gu0, nullptr, rwbuf);
      gemm_dual_k<EPI2_GU><<<dim3(16, 64, 1), blk256, 0, stream>>>(
          x2_bf, gateT + (size_t)e1 * wsz, upT + (size_t)e1 * wsz, e1, gu1, nullptr, rwbuf);
      gemm_down2_k<<<dim3(8, 64, 1), blk256, 0, stream>>>(
          gu0, gu1, downT + (size_t)e0 * wsz, downT + (size_t)e1 * wsz, out);
    }
  } else {
    for (int i = 0; i < E_; ++i) {
      gemm_dual_k<EPI2_GU><<<dim3(16, 64, 1), blk256, 0, stream>>>(
          x2_bf, gateT + (size_t)i * wsz, upT + (size_t)i * wsz, i, gu0, nullptr, rwbuf);
      EpiAux ad{}; ad.out2 = out;
      gemm_bf16k<EPI_DOWN><<<dim3(8, 64, 1), blk256, 0, stream>>>(
          gu0, IM_, 0, 0, 0, downT + (size_t)i * wsz, IM_, 0, 0, 0,
          0, 0, 0, IM_, ad);
    }
  }
}